// Round 1
// baseline (995.217 us; speedup 1.0000x reference)
//
#include <hip/hip_runtime.h>

#define HIDDEN 1152
#define HEADS  16
#define HDIM   72
#define DPAD   96
#define NB     2
#define TT     4096
#define BT     (NB*TT)  // 8192

typedef float  f32x4  __attribute__((ext_vector_type(4)));
typedef __bf16 bf16x8 __attribute__((ext_vector_type(8)));

static __device__ __forceinline__ unsigned short f2bf(float f){
    unsigned u = __builtin_bit_cast(unsigned, f);
    u = (u + 0x7FFFu + ((u >> 16) & 1u)) >> 16;   // RNE
    return (unsigned short)u;
}

__global__ __launch_bounds__(256) void k_convert_x(const float* __restrict__ x, unsigned short* __restrict__ xb){
    int i = (blockIdx.x*256 + threadIdx.x) * 4;   // 9437184 elems total
    float4 v = *reinterpret_cast<const float4*>(x + i);
    ushort4 o;
    o.x = f2bf(v.x); o.y = f2bf(v.y); o.z = f2bf(v.z); o.w = f2bf(v.w);
    *reinterpret_cast<ushort4*>(xb + i) = o;
}

__global__ __launch_bounds__(256) void k_wtrans(const float* __restrict__ w, unsigned short* __restrict__ wt){
    int i = blockIdx.x*256 + threadIdx.x;         // 1327104 elems
    int k = i / HIDDEN, n = i % HIDDEN;
    wt[n*HIDDEN + k] = f2bf(w[i]);
}

// MODE 0: Q -> padded [b][h][t][96], *scale ; 1: K -> padded ; 2: V -> [b][h][96][t] ; 3: fp32 out + bias
template<int MODE>
__global__ __launch_bounds__(256) void k_gemm(const unsigned short* __restrict__ A,
                                              const unsigned short* __restrict__ Bt,
                                              const float* __restrict__ bias,
                                              void* __restrict__ out, float scale){
    __shared__ __align__(16) unsigned short As[128][40];
    __shared__ __align__(16) unsigned short Bs[128][40];
    const int tid  = threadIdx.x;
    const int lane = tid & 63, wid = tid >> 6;
    const int wm = wid >> 1, wn = wid & 1;
    const int half = lane >> 4, q16 = lane & 15;
    const int m0 = blockIdx.y * 128, n0 = blockIdx.x * 128;

    f32x4 acc[4][4] = {};
    for(int k0 = 0; k0 < HIDDEN; k0 += 32){
        __syncthreads();
        #pragma unroll
        for(int it = 0; it < 2; ++it){
            int c = tid + it*256;           // 512 chunks of 16B
            int r = c >> 2, ch = c & 3;
            *reinterpret_cast<uint4*>(&As[r][ch*8]) =
                *reinterpret_cast<const uint4*>(A  + (m0+r)*HIDDEN + k0 + ch*8);
            *reinterpret_cast<uint4*>(&Bs[r][ch*8]) =
                *reinterpret_cast<const uint4*>(Bt + (n0+r)*HIDDEN + k0 + ch*8);
        }
        __syncthreads();
        bf16x8 af[4], bf[4];
        #pragma unroll
        for(int mi=0;mi<4;++mi) af[mi] = *reinterpret_cast<const bf16x8*>(&As[wm*64 + mi*16 + q16][half*8]);
        #pragma unroll
        for(int ni=0;ni<4;++ni) bf[ni] = *reinterpret_cast<const bf16x8*>(&Bs[wn*64 + ni*16 + q16][half*8]);
        #pragma unroll
        for(int mi=0;mi<4;++mi)
            #pragma unroll
            for(int ni=0;ni<4;++ni)
                acc[mi][ni] = __builtin_amdgcn_mfma_f32_16x16x32_bf16(af[mi], bf[ni], acc[mi][ni], 0,0,0);
    }
    #pragma unroll
    for(int mi=0;mi<4;++mi)
        #pragma unroll
        for(int ni=0;ni<4;++ni)
            #pragma unroll
            for(int j=0;j<4;++j){
                int row = m0 + wm*64 + mi*16 + half*4 + j;   // token index
                int col = n0 + wn*64 + ni*16 + q16;          // output feature
                float v = acc[mi][ni][j] + bias[col];
                if(MODE==0) v *= scale;
                if(MODE==0 || MODE==1){
                    int b = row >> 12, t = row & 4095;
                    int h = col / HDIM, d = col % HDIM;
                    ((unsigned short*)out)[((size_t)((b*HEADS + h)*TT) + t)*DPAD + d] = f2bf(v);
                } else if(MODE==2){
                    int b = row >> 12, t = row & 4095;
                    int h = col / HDIM, d = col % HDIM;
                    ((unsigned short*)out)[((size_t)((b*HEADS + h)*DPAD) + d)*TT + t] = f2bf(v);
                } else {
                    ((float*)out)[(size_t)row*HIDDEN + col] = v;
                }
            }
}

__global__ __launch_bounds__(256) void k_attn(const unsigned short* __restrict__ Qp,
                                              const unsigned short* __restrict__ Kp,
                                              const unsigned short* __restrict__ Vt,
                                              unsigned short* __restrict__ AO){
    __shared__ __align__(16) unsigned short Ks[64][104];
    __shared__ __align__(16) unsigned short Vs[96][72];
    __shared__ __align__(16) unsigned short Ps[4][16][72];
    const int tid  = threadIdx.x;
    const int lane = tid & 63, wid = tid >> 6;
    const int half = lane >> 4, q16 = lane & 15;
    const int blk = blockIdx.x;
    const int qt = blk & 63, h = (blk >> 6) & 15, b = blk >> 10;
    const int qbase = qt * 64;
    const int bh = b*HEADS + h;

    // Q fragments for this wave's 16 rows (K-dim = 96 padded -> 3 frags)
    const unsigned short* qptr = Qp + ((size_t)(bh*TT) + qbase + wid*16 + q16) * DPAD;
    bf16x8 qf[3];
    #pragma unroll
    for(int kk=0;kk<3;++kk) qf[kk] = *reinterpret_cast<const bf16x8*>(qptr + kk*32 + half*8);

    f32x4 accO[6] = {};
    float m[4], l[4];
    #pragma unroll
    for(int j=0;j<4;++j){ m[j] = -1e30f; l[j] = 0.f; }

    const unsigned short* kbase = Kp + (size_t)(bh*TT) * DPAD;
    const unsigned short* vbase = Vt + (size_t)(bh*DPAD) * TT;

    for(int kt0 = 0; kt0 < TT; kt0 += 64){
        __syncthreads();
        #pragma unroll
        for(int it=0; it<3; ++it){
            int c = tid + it*256;              // 768 chunks each
            { int r = c / 12, ch = c % 12;     // K tile: 64 rows x 96
              *reinterpret_cast<uint4*>(&Ks[r][ch*8]) =
                  *reinterpret_cast<const uint4*>(kbase + (size_t)(kt0 + r)*DPAD + ch*8); }
            { int d = c >> 3, ch = c & 7;      // V^T tile: 96 rows x 64
              *reinterpret_cast<uint4*>(&Vs[d][ch*8]) =
                  *reinterpret_cast<const uint4*>(vbase + (size_t)d*TT + kt0 + ch*8); }
        }
        __syncthreads();

        // S = Q K^T  (4 sub-tiles of 16 k-cols)
        f32x4 s[4] = {};
        #pragma unroll
        for(int kt=0;kt<4;++kt){
            #pragma unroll
            for(int kk=0;kk<3;++kk){
                bf16x8 kf = *reinterpret_cast<const bf16x8*>(&Ks[kt*16 + q16][kk*32 + half*8]);
                s[kt] = __builtin_amdgcn_mfma_f32_16x16x32_bf16(qf[kk], kf, s[kt], 0,0,0);
            }
        }
        // online softmax (row = half*4+j, 16 lanes of a group share a row-set)
        float alpha[4];
        #pragma unroll
        for(int j=0;j<4;++j){
            float tm = s[0][j];
            #pragma unroll
            for(int kt=1;kt<4;++kt) tm = fmaxf(tm, s[kt][j]);
            #pragma unroll
            for(int msk=1; msk<16; msk<<=1) tm = fmaxf(tm, __shfl_xor(tm, msk, 64));
            float mn = fmaxf(m[j], tm);
            alpha[j] = __expf(m[j] - mn);
            m[j] = mn;
        }
        float rs[4] = {0.f,0.f,0.f,0.f};
        float p[4][4];
        #pragma unroll
        for(int kt=0;kt<4;++kt)
            #pragma unroll
            for(int j=0;j<4;++j){ p[kt][j] = __expf(s[kt][j] - m[j]); rs[j] += p[kt][j]; }
        #pragma unroll
        for(int j=0;j<4;++j){
            float r = rs[j];
            #pragma unroll
            for(int msk=1; msk<16; msk<<=1) r += __shfl_xor(r, msk, 64);
            l[j] = l[j]*alpha[j] + r;
        }
        #pragma unroll
        for(int nt=0;nt<6;++nt)
            #pragma unroll
            for(int j=0;j<4;++j) accO[nt][j] *= alpha[j];
        // P (C-layout) -> LDS -> A-fragments
        #pragma unroll
        for(int kt=0;kt<4;++kt)
            #pragma unroll
            for(int j=0;j<4;++j) Ps[wid][half*4+j][kt*16+q16] = f2bf(p[kt][j]);
        #pragma unroll
        for(int kh=0; kh<2; ++kh){
            bf16x8 pf = *reinterpret_cast<const bf16x8*>(&Ps[wid][q16][kh*32 + half*8]);
            #pragma unroll
            for(int nt=0; nt<6; ++nt){
                bf16x8 vf = *reinterpret_cast<const bf16x8*>(&Vs[nt*16 + q16][kh*32 + half*8]);
                accO[nt] = __builtin_amdgcn_mfma_f32_16x16x32_bf16(pf, vf, accO[nt], 0,0,0);
            }
        }
    }
    // normalize + write attn output (bf16, [b*T][1152] row-major)
    #pragma unroll
    for(int nt=0;nt<6;++nt){
        int d = nt*16 + q16;
        if(d < HDIM){
            #pragma unroll
            for(int j=0;j<4;++j){
                int t = qbase + wid*16 + half*4 + j;
                AO[((size_t)(b*TT + t))*HIDDEN + h*HDIM + d] = f2bf(accO[nt][j] / l[j]);
            }
        }
    }
}

extern "C" void kernel_launch(void* const* d_in, const int* in_sizes, int n_in,
                              void* d_out, int out_size, void* d_ws, size_t ws_size,
                              hipStream_t stream) {
    const float* x  = (const float*)d_in[0];
    const float* wq = (const float*)d_in[1];
    const float* bq = (const float*)d_in[2];
    const float* wk = (const float*)d_in[3];
    const float* bk = (const float*)d_in[4];
    const float* wv = (const float*)d_in[5];
    const float* bv = (const float*)d_in[6];
    const float* wo = (const float*)d_in[7];
    const float* bo = (const float*)d_in[8];

    char* ws = (char*)d_ws;
    const size_t szXb = (size_t)BT*HIDDEN*2;          // 18874368
    const size_t szW  = (size_t)HIDDEN*HIDDEN*2;      // 2654208
    const size_t szQp = (size_t)NB*HEADS*TT*DPAD*2;   // 25165824

    unsigned short* Xb  = (unsigned short*)(ws);
    unsigned short* WTq = (unsigned short*)(ws + szXb);
    unsigned short* WTk = (unsigned short*)(ws + szXb + szW);
    unsigned short* WTv = (unsigned short*)(ws + szXb + 2*szW);
    unsigned short* WTo = (unsigned short*)(ws + szXb + 3*szW);
    unsigned short* Qp  = (unsigned short*)(ws + szXb + 4*szW);
    unsigned short* Kp  = (unsigned short*)(ws + szXb + 4*szW + szQp);
    unsigned short* Vt  = (unsigned short*)(ws + szXb + 4*szW + 2*szQp);
    unsigned short* AO  = (unsigned short*)(ws + szXb + 4*szW + 3*szQp);

    hipMemsetAsync(Qp, 0, szQp, stream);
    hipMemsetAsync(Kp, 0, szQp, stream);
    hipMemsetAsync(Vt, 0, szQp, stream);

    k_convert_x<<<BT*HIDDEN/1024, 256, 0, stream>>>(x, Xb);
    k_wtrans<<<HIDDEN*HIDDEN/256, 256, 0, stream>>>(wq, WTq);
    k_wtrans<<<HIDDEN*HIDDEN/256, 256, 0, stream>>>(wk, WTk);
    k_wtrans<<<HIDDEN*HIDDEN/256, 256, 0, stream>>>(wv, WTv);
    k_wtrans<<<HIDDEN*HIDDEN/256, 256, 0, stream>>>(wo, WTo);

    const float scale = 1.0f / sqrtf((float)HDIM);
    dim3 gg(HIDDEN/128, BT/128);
    k_gemm<0><<<gg, 256, 0, stream>>>(Xb, WTq, bq, Qp, scale);
    k_gemm<1><<<gg, 256, 0, stream>>>(Xb, WTk, bk, Kp, 1.0f);
    k_gemm<2><<<gg, 256, 0, stream>>>(Xb, WTv, bv, Vt, 1.0f);

    k_attn<<<NB*HEADS*(TT/64), 256, 0, stream>>>(Qp, Kp, Vt, AO);

    k_gemm<3><<<gg, 256, 0, stream>>>(AO, WTo, bo, d_out, 1.0f);
}

// Round 4
// 883.105 us; speedup vs baseline: 1.1270x; 1.1270x over previous
//
#include <hip/hip_runtime.h>

#define HIDDEN 1152
#define HEADS  16
#define HDIM   72
#define DPAD   96
#define NB     2
#define TT     4096
#define BT     (NB*TT)  // 8192

typedef float  f32x4   __attribute__((ext_vector_type(4)));
typedef __bf16 bf16x8  __attribute__((ext_vector_type(8)));

static __device__ __forceinline__ unsigned pkbf(float a, float b){
    unsigned r;
    asm("v_cvt_pk_bf16_f32 %0, %1, %2" : "=v"(r) : "v"(a), "v"(b));
    return r;
}
static __device__ __forceinline__ unsigned short f2bf(float f){
    unsigned u = __builtin_bit_cast(unsigned, f);
    u = (u + 0x7FFFu + ((u >> 16) & 1u)) >> 16;   // RNE
    return (unsigned short)u;
}
static __device__ __forceinline__ void gld16(const unsigned short* g, unsigned short* l){
    __builtin_amdgcn_global_load_lds((const __attribute__((address_space(1))) void*)g,
                                     (__attribute__((address_space(3))) void*)l, 16, 0, 0);
}

__global__ __launch_bounds__(256) void k_convert_x(const float* __restrict__ x, unsigned short* __restrict__ xb){
    int i = (blockIdx.x*256 + threadIdx.x) * 4;
    float4 v = *reinterpret_cast<const float4*>(x + i);
    uint2 p; p.x = pkbf(v.x, v.y); p.y = pkbf(v.z, v.w);
    *reinterpret_cast<uint2*>(xb + i) = p;
}

// tiled transpose+convert: w[k][n] (fp32) -> wt[n][k] (bf16)
__global__ __launch_bounds__(256) void k_wtrans(const float* __restrict__ w, unsigned short* __restrict__ wt){
    __shared__ __align__(16) unsigned short Ws[64][72];
    const int r0 = (blockIdx.x / 18) * 64, c0 = (blockIdx.x % 18) * 64;
    #pragma unroll
    for(int it=0; it<4; ++it){
        int idx = threadIdx.x + it*256;
        int r = idx >> 4, cq = (idx & 15) * 4;
        float4 v = *reinterpret_cast<const float4*>(w + (size_t)(r0+r)*HIDDEN + c0 + cq);
        uint2 p; p.x = pkbf(v.x, v.y); p.y = pkbf(v.z, v.w);
        *reinterpret_cast<uint2*>(&Ws[r][cq]) = p;
    }
    __syncthreads();
    #pragma unroll
    for(int it=0; it<4; ++it){
        int idx = threadIdx.x + it*256;
        int rr = idx >> 4, cq = (idx & 15) * 4;
        ushort4 o;
        o.x = Ws[cq+0][rr]; o.y = Ws[cq+1][rr]; o.z = Ws[cq+2][rr]; o.w = Ws[cq+3][rr];
        *reinterpret_cast<ushort4*>(wt + (size_t)(c0+rr)*HIDDEN + r0 + cq) = o;
    }
}

// MODE 0: Q -> [b][h][t][96] *scale; 1: K -> same; 2: V -> [b][h][96][t]; 3: fp32 out+bias
template<int MODE>
__global__ __launch_bounds__(256, 3) void k_gemm(const unsigned short* __restrict__ A,
                                                 const unsigned short* __restrict__ Bt,
                                                 const float* __restrict__ bias,
                                                 void* __restrict__ out, float scale){
    __shared__ __align__(16) unsigned short As[128*32];
    __shared__ __align__(16) unsigned short Bs[128*32];
    const int tid = threadIdx.x, lane = tid & 63, wid = tid >> 6;
    const int wm = wid >> 1, wn = wid & 1;
    const int half = lane >> 4, q16 = lane & 15;
    int lb = (blockIdx.x & 7) * 72 + (blockIdx.x >> 3);       // XCD-chunked swizzle (576 = 8*72)
    const int n0 = (lb % 9) * 128, m0 = (lb / 9) * 128;
    const int lr = lane >> 2, lc = (lane & 3) * 8;
    const unsigned short* ap = A  + (size_t)(m0 + wid*32 + lr)*HIDDEN + lc;
    const unsigned short* bp = Bt + (size_t)(n0 + wid*32 + lr)*HIDDEN + lc;
    unsigned short* as0 = As + (wid*32     )*32 + lane*8;
    unsigned short* as1 = As + (wid*32 + 16)*32 + lane*8;
    unsigned short* bs0 = Bs + (wid*32     )*32 + lane*8;
    unsigned short* bs1 = Bs + (wid*32 + 16)*32 + lane*8;

    f32x4 acc[4][4] = {};
    for(int k0 = 0; k0 < HIDDEN; k0 += 32){
        gld16(ap + k0,             as0);
        gld16(ap + k0 + 16*HIDDEN, as1);
        gld16(bp + k0,             bs0);
        gld16(bp + k0 + 16*HIDDEN, bs1);
        __syncthreads();
        bf16x8 af[4], bf[4];
        #pragma unroll
        for(int mi=0;mi<4;++mi) af[mi] = *reinterpret_cast<const bf16x8*>(As + (wm*64+mi*16+q16)*32 + half*8);
        #pragma unroll
        for(int ni=0;ni<4;++ni) bf[ni] = *reinterpret_cast<const bf16x8*>(Bs + (wn*64+ni*16+q16)*32 + half*8);
        #pragma unroll
        for(int mi=0;mi<4;++mi)
            #pragma unroll
            for(int ni=0;ni<4;++ni)
                acc[mi][ni] = __builtin_amdgcn_mfma_f32_16x16x32_bf16(af[mi], bf[ni], acc[mi][ni], 0,0,0);
        __syncthreads();
    }
    #pragma unroll
    for(int mi=0;mi<4;++mi)
        #pragma unroll
        for(int ni=0;ni<4;++ni)
            #pragma unroll
            for(int j=0;j<4;++j){
                int row = m0 + wm*64 + mi*16 + half*4 + j;   // token index
                int col = n0 + wn*64 + ni*16 + q16;          // output feature
                float v = acc[mi][ni][j] + bias[col];
                if(MODE==0) v *= scale;
                if(MODE==0 || MODE==1){
                    int bb = row >> 12, t = row & 4095;
                    int hh = col / HDIM, d = col % HDIM;
                    ((unsigned short*)out)[((size_t)((bb*HEADS + hh)*TT) + t)*DPAD + d] = f2bf(v);
                } else if(MODE==2){
                    int bb = row >> 12, t = row & 4095;
                    int hh = col / HDIM, d = col % HDIM;
                    ((unsigned short*)out)[((size_t)((bb*HEADS + hh)*DPAD) + d)*TT + t] = f2bf(v);
                } else {
                    ((float*)out)[(size_t)row*HIDDEN + col] = v;
                }
            }
}

// ROUND-1 attention, verbatim (known-PASS): 16x16 MFMA, DPAD=96, __expf, P via LDS
__global__ __launch_bounds__(256) void k_attn(const unsigned short* __restrict__ Qp,
                                              const unsigned short* __restrict__ Kp,
                                              const unsigned short* __restrict__ Vt,
                                              unsigned short* __restrict__ AO){
    __shared__ __align__(16) unsigned short Ks[64][104];
    __shared__ __align__(16) unsigned short Vs[96][72];
    __shared__ __align__(16) unsigned short Ps[4][16][72];
    const int tid  = threadIdx.x;
    const int lane = tid & 63, wid = tid >> 6;
    const int half = lane >> 4, q16 = lane & 15;
    const int blk = blockIdx.x;
    const int qt = blk & 63, h = (blk >> 6) & 15, b = blk >> 10;
    const int qbase = qt * 64;
    const int bh = b*HEADS + h;

    const unsigned short* qptr = Qp + ((size_t)(bh*TT) + qbase + wid*16 + q16) * DPAD;
    bf16x8 qf[3];
    #pragma unroll
    for(int kk=0;kk<3;++kk) qf[kk] = *reinterpret_cast<const bf16x8*>(qptr + kk*32 + half*8);

    f32x4 accO[6] = {};
    float m[4], l[4];
    #pragma unroll
    for(int j=0;j<4;++j){ m[j] = -1e30f; l[j] = 0.f; }

    const unsigned short* kbase = Kp + (size_t)(bh*TT) * DPAD;
    const unsigned short* vbase = Vt + (size_t)(bh*DPAD) * TT;

    for(int kt0 = 0; kt0 < TT; kt0 += 64){
        __syncthreads();
        #pragma unroll
        for(int it=0; it<3; ++it){
            int c = tid + it*256;
            { int r = c / 12, ch = c % 12;
              *reinterpret_cast<uint4*>(&Ks[r][ch*8]) =
                  *reinterpret_cast<const uint4*>(kbase + (size_t)(kt0 + r)*DPAD + ch*8); }
            { int d = c >> 3, ch = c & 7;
              *reinterpret_cast<uint4*>(&Vs[d][ch*8]) =
                  *reinterpret_cast<const uint4*>(vbase + (size_t)d*TT + kt0 + ch*8); }
        }
        __syncthreads();

        f32x4 s[4] = {};
        #pragma unroll
        for(int kt=0;kt<4;++kt){
            #pragma unroll
            for(int kk=0;kk<3;++kk){
                bf16x8 kf = *reinterpret_cast<const bf16x8*>(&Ks[kt*16 + q16][kk*32 + half*8]);
                s[kt] = __builtin_amdgcn_mfma_f32_16x16x32_bf16(qf[kk], kf, s[kt], 0,0,0);
            }
        }
        float alpha[4];
        #pragma unroll
        for(int j=0;j<4;++j){
            float tm = s[0][j];
            #pragma unroll
            for(int kt=1;kt<4;++kt) tm = fmaxf(tm, s[kt][j]);
            #pragma unroll
            for(int msk=1; msk<16; msk<<=1) tm = fmaxf(tm, __shfl_xor(tm, msk, 64));
            float mn = fmaxf(m[j], tm);
            alpha[j] = __expf(m[j] - mn);
            m[j] = mn;
        }
        float rs[4] = {0.f,0.f,0.f,0.f};
        float p[4][4];
        #pragma unroll
        for(int kt=0;kt<4;++kt)
            #pragma unroll
            for(int j=0;j<4;++j){ p[kt][j] = __expf(s[kt][j] - m[j]); rs[j] += p[kt][j]; }
        #pragma unroll
        for(int j=0;j<4;++j){
            float r = rs[j];
            #pragma unroll
            for(int msk=1; msk<16; msk<<=1) r += __shfl_xor(r, msk, 64);
            l[j] = l[j]*alpha[j] + r;
        }
        #pragma unroll
        for(int nt=0;nt<6;++nt)
            #pragma unroll
            for(int j=0;j<4;++j) accO[nt][j] *= alpha[j];
        #pragma unroll
        for(int kt=0;kt<4;++kt)
            #pragma unroll
            for(int j=0;j<4;++j) Ps[wid][half*4+j][kt*16+q16] = f2bf(p[kt][j]);
        #pragma unroll
        for(int kh=0; kh<2; ++kh){
            bf16x8 pf = *reinterpret_cast<const bf16x8*>(&Ps[wid][q16][kh*32 + half*8]);
            #pragma unroll
            for(int nt=0; nt<6; ++nt){
                bf16x8 vf = *reinterpret_cast<const bf16x8*>(&Vs[nt*16 + q16][kh*32 + half*8]);
                accO[nt] = __builtin_amdgcn_mfma_f32_16x16x32_bf16(pf, vf, accO[nt], 0,0,0);
            }
        }
    }
    #pragma unroll
    for(int nt=0;nt<6;++nt){
        int d = nt*16 + q16;
        if(d < HDIM){
            #pragma unroll
            for(int j=0;j<4;++j){
                int t = qbase + wid*16 + half*4 + j;
                AO[((size_t)(b*TT + t))*HIDDEN + h*HDIM + d] = f2bf(accO[nt][j] / l[j]);
            }
        }
    }
}

extern "C" void kernel_launch(void* const* d_in, const int* in_sizes, int n_in,
                              void* d_out, int out_size, void* d_ws, size_t ws_size,
                              hipStream_t stream) {
    const float* x  = (const float*)d_in[0];
    const float* wq = (const float*)d_in[1];
    const float* bq = (const float*)d_in[2];
    const float* wk = (const float*)d_in[3];
    const float* bk = (const float*)d_in[4];
    const float* wv = (const float*)d_in[5];
    const float* bv = (const float*)d_in[6];
    const float* wo = (const float*)d_in[7];
    const float* bo = (const float*)d_in[8];

    char* ws = (char*)d_ws;
    const size_t szXb = (size_t)BT*HIDDEN*2;          // 18874368
    const size_t szW  = (size_t)HIDDEN*HIDDEN*2;      // 2654208
    const size_t szQp = (size_t)NB*HEADS*TT*DPAD*2;   // 25165824

    unsigned short* Xb  = (unsigned short*)(ws);
    unsigned short* WTq = (unsigned short*)(ws + szXb);
    unsigned short* WTk = (unsigned short*)(ws + szXb + szW);
    unsigned short* WTv = (unsigned short*)(ws + szXb + 2*szW);
    unsigned short* WTo = (unsigned short*)(ws + szXb + 3*szW);
    unsigned short* Qp  = (unsigned short*)(ws + szXb + 4*szW);
    unsigned short* Kp  = (unsigned short*)(ws + szXb + 4*szW + szQp);
    unsigned short* Vt  = (unsigned short*)(ws + szXb + 4*szW + 2*szQp);
    unsigned short* AO  = (unsigned short*)(ws + szXb + 4*szW + 3*szQp);

    hipMemsetAsync(Qp, 0, 3*szQp, stream);            // zero d-padding of Q, K, V (contiguous)

    k_convert_x<<<BT*HIDDEN/1024, 256, 0, stream>>>(x, Xb);
    k_wtrans<<<324, 256, 0, stream>>>(wq, WTq);
    k_wtrans<<<324, 256, 0, stream>>>(wk, WTk);
    k_wtrans<<<324, 256, 0, stream>>>(wv, WTv);
    k_wtrans<<<324, 256, 0, stream>>>(wo, WTo);

    const float qscale = 1.0f / sqrtf(72.0f);
    k_gemm<0><<<576, 256, 0, stream>>>(Xb, WTq, bq, Qp, qscale);
    k_gemm<1><<<576, 256, 0, stream>>>(Xb, WTk, bk, Kp, 1.0f);
    k_gemm<2><<<576, 256, 0, stream>>>(Xb, WTv, bv, Vt, 1.0f);

    k_attn<<<NB*HEADS*(TT/64), 256, 0, stream>>>(Qp, Kp, Vt, AO);

    k_gemm<3><<<576, 256, 0, stream>>>(AO, WTo, bo, d_out, 1.0f);
}

// Round 5
// 710.487 us; speedup vs baseline: 1.4008x; 1.2430x over previous
//
#include <hip/hip_runtime.h>

#define HIDDEN 1152
#define HEADS  16
#define HDIM   72
#define DPAD   96
#define NB     2
#define TT     4096
#define BT     (NB*TT)  // 8192

#define KSTR   128     // Ks row stride (shorts): 16 granules of 8, XOR headroom
#define VSTR   64      // Vs row stride
#define PSTR   64      // Ps row stride

typedef float  f32x4   __attribute__((ext_vector_type(4)));
typedef __bf16 bf16x8  __attribute__((ext_vector_type(8)));

static __device__ __forceinline__ unsigned pkbf(float a, float b){
    unsigned r;
    asm("v_cvt_pk_bf16_f32 %0, %1, %2" : "=v"(r) : "v"(a), "v"(b));
    return r;
}
static __device__ __forceinline__ unsigned short f2b(float f){
    return (unsigned short)pkbf(f, f);
}
static __device__ __forceinline__ void gld16(const unsigned short* g, unsigned short* l){
    __builtin_amdgcn_global_load_lds((const __attribute__((address_space(1))) void*)g,
                                     (__attribute__((address_space(3))) void*)l, 16, 0, 0);
}

__global__ __launch_bounds__(256) void k_convert_x(const float* __restrict__ x, unsigned short* __restrict__ xb){
    int i = (blockIdx.x*256 + threadIdx.x) * 4;
    float4 v = *reinterpret_cast<const float4*>(x + i);
    uint2 p; p.x = pkbf(v.x, v.y); p.y = pkbf(v.z, v.w);
    *reinterpret_cast<uint2*>(xb + i) = p;
}

// tiled transpose+convert: w[k][n] (fp32) -> wt[n][k] (bf16)
__global__ __launch_bounds__(256) void k_wtrans(const float* __restrict__ w, unsigned short* __restrict__ wt){
    __shared__ __align__(16) unsigned short Ws[64][72];
    const int r0 = (blockIdx.x / 18) * 64, c0 = (blockIdx.x % 18) * 64;
    #pragma unroll
    for(int it=0; it<4; ++it){
        int idx = threadIdx.x + it*256;
        int r = idx >> 4, cq = (idx & 15) * 4;
        float4 v = *reinterpret_cast<const float4*>(w + (size_t)(r0+r)*HIDDEN + c0 + cq);
        uint2 p; p.x = pkbf(v.x, v.y); p.y = pkbf(v.z, v.w);
        *reinterpret_cast<uint2*>(&Ws[r][cq]) = p;
    }
    __syncthreads();
    #pragma unroll
    for(int it=0; it<4; ++it){
        int idx = threadIdx.x + it*256;
        int rr = idx >> 4, cq = (idx & 15) * 4;
        ushort4 o;
        o.x = Ws[cq+0][rr]; o.y = Ws[cq+1][rr]; o.z = Ws[cq+2][rr]; o.w = Ws[cq+3][rr];
        *reinterpret_cast<ushort4*>(wt + (size_t)(c0+rr)*HIDDEN + r0 + cq) = o;
    }
}

// MODE 0: Q -> [b][h][t][96] *scale; 1: K -> same; 2: V -> [b][h][96][t]; 3: fp32 out+bias
template<int MODE>
__global__ __launch_bounds__(256, 3) void k_gemm(const unsigned short* __restrict__ A,
                                                 const unsigned short* __restrict__ Bt,
                                                 const float* __restrict__ bias,
                                                 void* __restrict__ out, float scale){
    __shared__ __align__(16) unsigned short As[128*32];
    __shared__ __align__(16) unsigned short Bs[128*32];
    const int tid = threadIdx.x, lane = tid & 63, wid = tid >> 6;
    const int wm = wid >> 1, wn = wid & 1;
    const int half = lane >> 4, q16 = lane & 15;
    int lb = (blockIdx.x & 7) * 72 + (blockIdx.x >> 3);       // XCD-chunked swizzle (576 = 8*72)
    const int n0 = (lb % 9) * 128, m0 = (lb / 9) * 128;
    const int lr = lane >> 2, lc = (lane & 3) * 8;
    const unsigned short* ap = A  + (size_t)(m0 + wid*32 + lr)*HIDDEN + lc;
    const unsigned short* bp = Bt + (size_t)(n0 + wid*32 + lr)*HIDDEN + lc;
    unsigned short* as0 = As + (wid*32     )*32 + lane*8;
    unsigned short* as1 = As + (wid*32 + 16)*32 + lane*8;
    unsigned short* bs0 = Bs + (wid*32     )*32 + lane*8;
    unsigned short* bs1 = Bs + (wid*32 + 16)*32 + lane*8;

    f32x4 acc[4][4] = {};
    for(int k0 = 0; k0 < HIDDEN; k0 += 32){
        gld16(ap + k0,             as0);
        gld16(ap + k0 + 16*HIDDEN, as1);
        gld16(bp + k0,             bs0);
        gld16(bp + k0 + 16*HIDDEN, bs1);
        __syncthreads();
        bf16x8 af[4], bf[4];
        #pragma unroll
        for(int mi=0;mi<4;++mi) af[mi] = *reinterpret_cast<const bf16x8*>(As + (wm*64+mi*16+q16)*32 + half*8);
        #pragma unroll
        for(int ni=0;ni<4;++ni) bf[ni] = *reinterpret_cast<const bf16x8*>(Bs + (wn*64+ni*16+q16)*32 + half*8);
        #pragma unroll
        for(int mi=0;mi<4;++mi)
            #pragma unroll
            for(int ni=0;ni<4;++ni)
                acc[mi][ni] = __builtin_amdgcn_mfma_f32_16x16x32_bf16(af[mi], bf[ni], acc[mi][ni], 0,0,0);
        __syncthreads();
    }
    #pragma unroll
    for(int mi=0;mi<4;++mi)
        #pragma unroll
        for(int ni=0;ni<4;++ni)
            #pragma unroll
            for(int j=0;j<4;++j){
                int row = m0 + wm*64 + mi*16 + half*4 + j;   // token index
                int col = n0 + wn*64 + ni*16 + q16;          // output feature
                float v = acc[mi][ni][j] + bias[col];
                if(MODE==0) v *= scale;
                if(MODE==0 || MODE==1){
                    int bb = row >> 12, t = row & 4095;
                    int hh = col / HDIM, d = col % HDIM;
                    ((unsigned short*)out)[((size_t)((bb*HEADS + hh)*TT) + t)*DPAD + d] = f2b(v);
                } else if(MODE==2){
                    int bb = row >> 12, t = row & 4095;
                    int hh = col / HDIM, d = col % HDIM;
                    ((unsigned short*)out)[((size_t)((bb*HEADS + hh)*DPAD) + d)*TT + t] = f2b(v);
                } else {
                    ((float*)out)[(size_t)row*HIDDEN + col] = v;
                }
            }
}

// flash attention: 16x16 MFMA core (verified), 128 q-rows/block (2 subtiles x 4 waves x 16),
// XOR-swizzled LDS (both-sides, reg-staged), exp2 softmax (log2e folded into Q), nt<5.
__global__ __launch_bounds__(256) void k_attn(const unsigned short* __restrict__ Qp,
                                              const unsigned short* __restrict__ Kp,
                                              const unsigned short* __restrict__ Vt,
                                              unsigned short* __restrict__ AO){
    __shared__ __align__(16) unsigned short Ks[64*KSTR];      // 16 KB
    __shared__ __align__(16) unsigned short Vs[80*VSTR];      // 10 KB
    __shared__ __align__(16) unsigned short Ps[4][16*PSTR];   // 8 KB
    const int tid  = threadIdx.x;
    const int lane = tid & 63, wid = tid >> 6;
    const int half = lane >> 4, q16 = lane & 15;
    const int sw7  = q16 & 7;                 // row&7 for all swizzled reads (rows = x*16+q16)

    int lb = ((blockIdx.x & 7) << 7) | (blockIdx.x >> 3);   // XCD-chunked (1024 = 8*128)
    const int qt = lb & 31, h = (lb >> 5) & 15, b = lb >> 9;
    const int qbase = qt * 128;
    const int bh = b*HEADS + h;

    const unsigned short* kbase = Kp + (size_t)(bh*TT) * DPAD;
    const unsigned short* vbase = Vt + (size_t)(bh*DPAD) * TT;

    // Q fragments for 2 q-subtiles x 16 rows
    bf16x8 qf[2][3];
    #pragma unroll
    for(int u=0;u<2;++u){
        const unsigned short* qptr = Qp + ((size_t)(bh*TT) + qbase + u*64 + wid*16 + q16) * DPAD;
        #pragma unroll
        for(int kk=0;kk<3;++kk) qf[u][kk] = *reinterpret_cast<const bf16x8*>(qptr + kk*32 + half*8);
    }

    f32x4 accO[2][5] = {};
    float m[2][4], l[2][4];
    #pragma unroll
    for(int u=0;u<2;++u)
        #pragma unroll
        for(int j=0;j<4;++j){ m[u][j] = -1e30f; l[u][j] = 0.f; }

    for(int kt0 = 0; kt0 < TT; kt0 += 64){
        __syncthreads();
        // stage K (64x96) and V^T (80x64), granule-XOR swizzled
        #pragma unroll
        for(int it=0; it<6; ++it){
            int c = tid + it*256;
            if(c < 768){
                int r = c/12, ch = c - r*12;
                uint4 v = *reinterpret_cast<const uint4*>(kbase + (size_t)(kt0 + r)*DPAD + ch*8);
                *reinterpret_cast<uint4*>(&Ks[r*KSTR + ((ch ^ (r&7))<<3)]) = v;
            } else if(c < 1408){
                int c2 = c - 768;
                int d = c2 >> 3, ch = c2 & 7;
                uint4 v = *reinterpret_cast<const uint4*>(vbase + (size_t)d*TT + kt0 + ch*8);
                *reinterpret_cast<uint4*>(&Vs[d*VSTR + ((ch ^ (d&7))<<3)]) = v;
            }
        }
        __syncthreads();

        // S = Q K^T for both q-subtiles (kf shared)
        f32x4 s[2][4] = {};
        #pragma unroll
        for(int kt=0;kt<4;++kt){
            #pragma unroll
            for(int kk=0;kk<3;++kk){
                bf16x8 kf = *reinterpret_cast<const bf16x8*>(&Ks[(kt*16+q16)*KSTR + (((kk*4+half) ^ sw7)<<3)]);
                s[0][kt] = __builtin_amdgcn_mfma_f32_16x16x32_bf16(qf[0][kk], kf, s[0][kt], 0,0,0);
                s[1][kt] = __builtin_amdgcn_mfma_f32_16x16x32_bf16(qf[1][kk], kf, s[1][kt], 0,0,0);
            }
        }

        #pragma unroll
        for(int u=0;u<2;++u){
            // online softmax (row = half*4+j; 16 lanes reduce over kv)
            float alpha[4];
            #pragma unroll
            for(int j=0;j<4;++j){
                float tm = s[u][0][j];
                #pragma unroll
                for(int kt=1;kt<4;++kt) tm = fmaxf(tm, s[u][kt][j]);
                #pragma unroll
                for(int msk=1; msk<16; msk<<=1) tm = fmaxf(tm, __shfl_xor(tm, msk, 64));
                float mn = fmaxf(m[u][j], tm);
                alpha[j] = __builtin_amdgcn_exp2f(m[u][j] - mn);
                m[u][j] = mn;
            }
            float rs[4] = {0.f,0.f,0.f,0.f};
            float p[4][4];
            #pragma unroll
            for(int kt=0;kt<4;++kt)
                #pragma unroll
                for(int j=0;j<4;++j){
                    p[kt][j] = __builtin_amdgcn_exp2f(s[u][kt][j] - m[u][j]);
                    rs[j] += p[kt][j];
                }
            #pragma unroll
            for(int j=0;j<4;++j){
                float r = rs[j];
                #pragma unroll
                for(int msk=1; msk<16; msk<<=1) r += __shfl_xor(r, msk, 64);
                l[u][j] = l[u][j]*alpha[j] + r;
            }
            #pragma unroll
            for(int nt=0;nt<5;++nt)
                #pragma unroll
                for(int j=0;j<4;++j) accO[u][nt][j] *= alpha[j];
            // P (C-layout) -> swizzled LDS
            #pragma unroll
            for(int kt=0;kt<4;++kt)
                #pragma unroll
                for(int j=0;j<4;++j){
                    int rloc = half*4 + j;
                    Ps[wid][rloc*PSTR + (((kt*2 + (q16>>3)) ^ (rloc&7))<<3) + (q16&7)] = f2b(p[kt][j]);
                }
            // PV: A = P[16 q][64 kv], B = V^T[d][kv]
            #pragma unroll
            for(int kh=0; kh<2; ++kh){
                bf16x8 pf = *reinterpret_cast<const bf16x8*>(&Ps[wid][q16*PSTR + (((kh*4+half) ^ sw7)<<3)]);
                #pragma unroll
                for(int nt=0; nt<5; ++nt){
                    bf16x8 vf = *reinterpret_cast<const bf16x8*>(&Vs[(nt*16+q16)*VSTR + (((kh*4+half) ^ sw7)<<3)]);
                    accO[u][nt] = __builtin_amdgcn_mfma_f32_16x16x32_bf16(pf, vf, accO[u][nt], 0,0,0);
                }
            }
        }
    }
    // epilogue
    #pragma unroll
    for(int u=0;u<2;++u)
        #pragma unroll
        for(int nt=0;nt<5;++nt){
            int d = nt*16 + q16;
            if(d < HDIM){
                #pragma unroll
                for(int j=0;j<4;++j){
                    int t = qbase + u*64 + wid*16 + half*4 + j;
                    AO[((size_t)(b*TT + t))*HIDDEN + h*HDIM + d] = f2b(accO[u][nt][j] / l[u][j]);
                }
            }
        }
}

extern "C" void kernel_launch(void* const* d_in, const int* in_sizes, int n_in,
                              void* d_out, int out_size, void* d_ws, size_t ws_size,
                              hipStream_t stream) {
    const float* x  = (const float*)d_in[0];
    const float* wq = (const float*)d_in[1];
    const float* bq = (const float*)d_in[2];
    const float* wk = (const float*)d_in[3];
    const float* bk = (const float*)d_in[4];
    const float* wv = (const float*)d_in[5];
    const float* bv = (const float*)d_in[6];
    const float* wo = (const float*)d_in[7];
    const float* bo = (const float*)d_in[8];

    char* ws = (char*)d_ws;
    const size_t szXb = (size_t)BT*HIDDEN*2;          // 18874368
    const size_t szW  = (size_t)HIDDEN*HIDDEN*2;      // 2654208
    const size_t szQp = (size_t)NB*HEADS*TT*DPAD*2;   // 25165824

    unsigned short* Xb  = (unsigned short*)(ws);
    unsigned short* WTq = (unsigned short*)(ws + szXb);
    unsigned short* WTk = (unsigned short*)(ws + szXb + szW);
    unsigned short* WTv = (unsigned short*)(ws + szXb + 2*szW);
    unsigned short* WTo = (unsigned short*)(ws + szXb + 3*szW);
    unsigned short* Qp  = (unsigned short*)(ws + szXb + 4*szW);
    unsigned short* Kp  = (unsigned short*)(ws + szXb + 4*szW + szQp);
    unsigned short* Vt  = (unsigned short*)(ws + szXb + 4*szW + 2*szQp);
    unsigned short* AO  = (unsigned short*)(ws + szXb + 4*szW + 3*szQp);

    hipMemsetAsync(Qp, 0, 3*szQp, stream);            // zero d-padding of Q, K, V (contiguous)

    k_convert_x<<<BT*HIDDEN/1024, 256, 0, stream>>>(x, Xb);
    k_wtrans<<<324, 256, 0, stream>>>(wq, WTq);
    k_wtrans<<<324, 256, 0, stream>>>(wk, WTk);
    k_wtrans<<<324, 256, 0, stream>>>(wv, WTv);
    k_wtrans<<<324, 256, 0, stream>>>(wo, WTo);

    const float qscale = (1.0f / sqrtf(72.0f)) * 1.44269504f;  // fold log2(e) for exp2 softmax
    k_gemm<0><<<576, 256, 0, stream>>>(Xb, WTq, bq, Qp, qscale);
    k_gemm<1><<<576, 256, 0, stream>>>(Xb, WTk, bk, Kp, 1.0f);
    k_gemm<2><<<576, 256, 0, stream>>>(Xb, WTv, bv, Vt, 1.0f);

    k_attn<<<NB*HEADS*(TT/128), 256, 0, stream>>>(Qp, Kp, Vt, AO);

    k_gemm<3><<<576, 256, 0, stream>>>(AO, WTo, bo, d_out, 1.0f);
}

// Round 6
// 529.963 us; speedup vs baseline: 1.8779x; 1.3406x over previous
//
#include <hip/hip_runtime.h>

#define HIDDEN 1152
#define HEADS  16
#define HDIM   72
#define DPAD   96
#define NB     2
#define TT     4096
#define BT     (NB*TT)  // 8192

#define KSTR   128     // Ks row stride (shorts): 16 granules of 8
#define VSTR   64      // Vs row stride
#define PSTRD  36      // PsT row stride (dwords): 16B-aligned b128 reads

typedef float  f32x4   __attribute__((ext_vector_type(4)));
typedef __bf16 bf16x8  __attribute__((ext_vector_type(8)));

static __device__ __forceinline__ unsigned pkbf(float a, float b){
    unsigned r;
    asm("v_cvt_pk_bf16_f32 %0, %1, %2" : "=v"(r) : "v"(a), "v"(b));
    return r;
}
static __device__ __forceinline__ unsigned short f2b(float f){
    return (unsigned short)pkbf(f, f);
}
static __device__ __forceinline__ void gld16(const unsigned short* g, unsigned short* l){
    __builtin_amdgcn_global_load_lds((const __attribute__((address_space(1))) void*)g,
                                     (__attribute__((address_space(3))) void*)l, 16, 0, 0);
}

__global__ __launch_bounds__(256) void k_convert_x(const float* __restrict__ x, unsigned short* __restrict__ xb){
    int i = (blockIdx.x*256 + threadIdx.x) * 4;
    float4 v = *reinterpret_cast<const float4*>(x + i);
    uint2 p; p.x = pkbf(v.x, v.y); p.y = pkbf(v.z, v.w);
    *reinterpret_cast<uint2*>(xb + i) = p;
}

// tiled transpose+convert: w[k][n] (fp32) -> wt[n][k] (bf16)
__global__ __launch_bounds__(256) void k_wtrans(const float* __restrict__ w, unsigned short* __restrict__ wt){
    __shared__ __align__(16) unsigned short Ws[64][72];
    const int r0 = (blockIdx.x / 18) * 64, c0 = (blockIdx.x % 18) * 64;
    #pragma unroll
    for(int it=0; it<4; ++it){
        int idx = threadIdx.x + it*256;
        int r = idx >> 4, cq = (idx & 15) * 4;
        float4 v = *reinterpret_cast<const float4*>(w + (size_t)(r0+r)*HIDDEN + c0 + cq);
        uint2 p; p.x = pkbf(v.x, v.y); p.y = pkbf(v.z, v.w);
        *reinterpret_cast<uint2*>(&Ws[r][cq]) = p;
    }
    __syncthreads();
    #pragma unroll
    for(int it=0; it<4; ++it){
        int idx = threadIdx.x + it*256;
        int rr = idx >> 4, cq = (idx & 15) * 4;
        ushort4 o;
        o.x = Ws[cq+0][rr]; o.y = Ws[cq+1][rr]; o.z = Ws[cq+2][rr]; o.w = Ws[cq+3][rr];
        *reinterpret_cast<ushort4*>(wt + (size_t)(c0+rr)*HIDDEN + r0 + cq) = o;
    }
}

// MODE 0: Q -> [b][h][t][96] *scale; 1: K -> same; 2: V -> [b][h][96][t]; 3: fp32 out+bias
template<int MODE>
__global__ __launch_bounds__(256, 3) void k_gemm(const unsigned short* __restrict__ A,
                                                 const unsigned short* __restrict__ Bt,
                                                 const float* __restrict__ bias,
                                                 void* __restrict__ out, float scale){
    __shared__ __align__(16) unsigned short As[128*32];
    __shared__ __align__(16) unsigned short Bs[128*32];
    const int tid = threadIdx.x, lane = tid & 63, wid = tid >> 6;
    const int wm = wid >> 1, wn = wid & 1;
    const int half = lane >> 4, q16 = lane & 15;
    int lb = (blockIdx.x & 7) * 72 + (blockIdx.x >> 3);       // XCD-chunked swizzle (576 = 8*72)
    const int n0 = (lb % 9) * 128, m0 = (lb / 9) * 128;
    const int lr = lane >> 2, lc = (lane & 3) * 8;
    const unsigned short* ap = A  + (size_t)(m0 + wid*32 + lr)*HIDDEN + lc;
    const unsigned short* bp = Bt + (size_t)(n0 + wid*32 + lr)*HIDDEN + lc;
    unsigned short* as0 = As + (wid*32     )*32 + lane*8;
    unsigned short* as1 = As + (wid*32 + 16)*32 + lane*8;
    unsigned short* bs0 = Bs + (wid*32     )*32 + lane*8;
    unsigned short* bs1 = Bs + (wid*32 + 16)*32 + lane*8;

    f32x4 acc[4][4] = {};
    for(int k0 = 0; k0 < HIDDEN; k0 += 32){
        gld16(ap + k0,             as0);
        gld16(ap + k0 + 16*HIDDEN, as1);
        gld16(bp + k0,             bs0);
        gld16(bp + k0 + 16*HIDDEN, bs1);
        __syncthreads();
        bf16x8 af[4], bf[4];
        #pragma unroll
        for(int mi=0;mi<4;++mi) af[mi] = *reinterpret_cast<const bf16x8*>(As + (wm*64+mi*16+q16)*32 + half*8);
        #pragma unroll
        for(int ni=0;ni<4;++ni) bf[ni] = *reinterpret_cast<const bf16x8*>(Bs + (wn*64+ni*16+q16)*32 + half*8);
        #pragma unroll
        for(int mi=0;mi<4;++mi)
            #pragma unroll
            for(int ni=0;ni<4;++ni)
                acc[mi][ni] = __builtin_amdgcn_mfma_f32_16x16x32_bf16(af[mi], bf[ni], acc[mi][ni], 0,0,0);
        __syncthreads();
    }
    #pragma unroll
    for(int mi=0;mi<4;++mi)
        #pragma unroll
        for(int ni=0;ni<4;++ni)
            #pragma unroll
            for(int j=0;j<4;++j){
                int row = m0 + wm*64 + mi*16 + half*4 + j;   // token index
                int col = n0 + wn*64 + ni*16 + q16;          // output feature
                float v = acc[mi][ni][j] + bias[col];
                if(MODE==0) v *= scale;
                if(MODE==0 || MODE==1){
                    int bb = row >> 12, t = row & 4095;
                    int hh = col / HDIM, d = col % HDIM;
                    ((unsigned short*)out)[((size_t)((bb*HEADS + hh)*TT) + t)*DPAD + d] = f2b(v);
                } else if(MODE==2){
                    int bb = row >> 12, t = row & 4095;
                    int hh = col / HDIM, d = col % HDIM;
                    ((unsigned short*)out)[((size_t)((bb*HEADS + hh)*DPAD) + d)*TT + t] = f2b(v);
                } else {
                    ((float*)out)[(size_t)row*HIDDEN + col] = v;
                }
            }
}

// flash attention: 16x16 MFMA, SWAPPED QK^T (S^T), per-lane-q softmax, kv-linear P^T via LDS,
// defer-max rescale (THR=8 log2), 128 q-rows/block, XOR-swizzled K/V staging.
__global__ __launch_bounds__(256) void k_attn(const unsigned short* __restrict__ Qp,
                                              const unsigned short* __restrict__ Kp,
                                              const unsigned short* __restrict__ Vt,
                                              unsigned short* __restrict__ AO){
    __shared__ __align__(16) unsigned short Ks[64*KSTR];      // 16 KB
    __shared__ __align__(16) unsigned short Vs[80*VSTR];      // 10 KB
    __shared__ __align__(16) unsigned int   PsT[4][16*PSTRD]; // 9 KB: row q, dword D = kv pair (2D,2D+1)
    const int tid  = threadIdx.x;
    const int lane = tid & 63, wid = tid >> 6;
    const int g    = lane >> 4, q16 = lane & 15;
    const int sw7  = q16 & 7;

    int lb = ((blockIdx.x & 7) << 7) | (blockIdx.x >> 3);   // XCD-chunked (1024 = 8*128)
    const int qt = lb & 31, h = (lb >> 5) & 15, b = lb >> 9;
    const int qbase = qt * 128;
    const int bh = b*HEADS + h;

    const unsigned short* kbase = Kp + (size_t)(bh*TT) * DPAD;
    const unsigned short* vbase = Vt + (size_t)(bh*DPAD) * TT;

    // zero Ks granules 10,11 (d in [80,96)) once; staging never rewrites them
    if(tid < 128){
        int r = tid >> 1, gi = 10 + (tid & 1);
        uint4 z = {0,0,0,0};
        *reinterpret_cast<uint4*>(&Ks[r*KSTR + ((gi ^ (r&7))<<3)]) = z;
    }

    // Q fragments: 2 q-subtiles x 16 rows; B-operand: row q = q16, k-slot g*8+e -> d = kk*32+g*8+e
    bf16x8 qf[2][3];
    #pragma unroll
    for(int u=0;u<2;++u){
        const unsigned short* qptr = Qp + ((size_t)(bh*TT) + qbase + u*64 + wid*16 + q16) * DPAD;
        #pragma unroll
        for(int kk=0;kk<3;++kk) qf[u][kk] = *reinterpret_cast<const bf16x8*>(qptr + kk*32 + g*8);
    }

    f32x4 accO[2][5] = {};
    float m[2] = {-1e30f, -1e30f};
    float l[2] = {0.f, 0.f};

    for(int kt0 = 0; kt0 < TT; kt0 += 64){
        __syncthreads();
        // stage K (64 rows x d<80, 10 chunks) + V^T (80 rows x 64, 8 chunks) = 1280 chunks, XOR-swizzled
        #pragma unroll
        for(int it=0; it<5; ++it){
            int c = tid + it*256;
            if(c < 640){
                int r = c/10, ch = c - r*10;
                uint4 v = *reinterpret_cast<const uint4*>(kbase + (size_t)(kt0 + r)*DPAD + ch*8);
                *reinterpret_cast<uint4*>(&Ks[r*KSTR + ((ch ^ (r&7))<<3)]) = v;
            } else {
                int c2 = c - 640;
                int d = c2 >> 3, ch = c2 & 7;
                uint4 v = *reinterpret_cast<const uint4*>(vbase + (size_t)d*TT + kt0 + ch*8);
                *reinterpret_cast<uint4*>(&Vs[d*VSTR + ((ch ^ (d&7))<<3)]) = v;
            }
        }
        __syncthreads();

        // S^T[kv][q] = mfma(A=K, B=Q): lane holds col q=q16, rows kv = 16kt + 4g + j
        f32x4 s[2][4] = {};
        #pragma unroll
        for(int kt=0;kt<4;++kt){
            #pragma unroll
            for(int kk=0;kk<3;++kk){
                bf16x8 kf = *reinterpret_cast<const bf16x8*>(&Ks[(kt*16+q16)*KSTR + (((kk*4+g) ^ sw7)<<3)]);
                s[0][kt] = __builtin_amdgcn_mfma_f32_16x16x32_bf16(kf, qf[0][kk], s[0][kt], 0,0,0);
                s[1][kt] = __builtin_amdgcn_mfma_f32_16x16x32_bf16(kf, qf[1][kk], s[1][kt], 0,0,0);
            }
        }

        #pragma unroll
        for(int u=0;u<2;++u){
            // max over this lane's 16 kv + 2-step cross-g reduce (lanes sharing q16)
            float t0 = fmaxf(fmaxf(s[u][0][0],s[u][0][1]), fmaxf(s[u][0][2],s[u][0][3]));
            float t1 = fmaxf(fmaxf(s[u][1][0],s[u][1][1]), fmaxf(s[u][1][2],s[u][1][3]));
            float t2 = fmaxf(fmaxf(s[u][2][0],s[u][2][1]), fmaxf(s[u][2][2],s[u][2][3]));
            float t3 = fmaxf(fmaxf(s[u][3][0],s[u][3][1]), fmaxf(s[u][3][2],s[u][3][3]));
            float tm = fmaxf(fmaxf(t0,t1), fmaxf(t2,t3));
            tm = fmaxf(tm, __shfl_xor(tm, 16, 64));
            tm = fmaxf(tm, __shfl_xor(tm, 32, 64));
            if(__any(tm > m[u] + 8.0f)){                       // defer-max rescale
                float mn = fmaxf(m[u], tm);
                float al = __builtin_amdgcn_exp2f(m[u] - mn);
                l[u] *= al;  m[u] = mn;
                float aj[4];
                #pragma unroll
                for(int j=0;j<4;++j) aj[j] = __shfl(al, (lane & 48) | (4*g + j), 64);
                #pragma unroll
                for(int nt=0;nt<5;++nt)
                    #pragma unroll
                    for(int j=0;j<4;++j) accO[u][nt][j] *= aj[j];
            }
            // P = exp2(S - m), kv-linear P^T rows: dword 8kt+2g+jj = kv pair (16kt+4g+2jj, +1)
            float sum = 0.f;
            #pragma unroll
            for(int kt=0;kt<4;++kt){
                float p0 = __builtin_amdgcn_exp2f(s[u][kt][0] - m[u]);
                float p1 = __builtin_amdgcn_exp2f(s[u][kt][1] - m[u]);
                float p2 = __builtin_amdgcn_exp2f(s[u][kt][2] - m[u]);
                float p3 = __builtin_amdgcn_exp2f(s[u][kt][3] - m[u]);
                sum += (p0 + p1) + (p2 + p3);
                uint2 w; w.x = pkbf(p0, p1); w.y = pkbf(p2, p3);
                *reinterpret_cast<uint2*>(&PsT[wid][q16*PSTRD + 8*kt + 2*g]) = w;
            }
            sum += __shfl_xor(sum, 16, 64);
            sum += __shfl_xor(sum, 32, 64);
            l[u] += sum;

            // PV: A = P[q][kv] (row q=q16, k-slot -> kv = kh*32+g*8+e = dwords 16kh+4g+0..3)
            #pragma unroll
            for(int kh=0; kh<2; ++kh){
                bf16x8 pf = *reinterpret_cast<const bf16x8*>(&PsT[wid][q16*PSTRD + 16*kh + 4*g]);
                #pragma unroll
                for(int nt=0; nt<5; ++nt){
                    bf16x8 vf = *reinterpret_cast<const bf16x8*>(&Vs[(nt*16+q16)*VSTR + (((kh*4+g) ^ sw7)<<3)]);
                    accO[u][nt] = __builtin_amdgcn_mfma_f32_16x16x32_bf16(pf, vf, accO[u][nt], 0,0,0);
                }
            }
        }
    }
    // epilogue: accO row q' = 4g+j needs l of q' (lives at lanes with lane&15 = q')
    #pragma unroll
    for(int u=0;u<2;++u){
        float linv[4];
        #pragma unroll
        for(int j=0;j<4;++j){
            float lj = __shfl(l[u], (lane & 48) | (4*g + j), 64);
            linv[j] = 1.0f / lj;
        }
        #pragma unroll
        for(int nt=0;nt<5;++nt){
            int d = nt*16 + q16;
            if(d < HDIM){
                #pragma unroll
                for(int j=0;j<4;++j){
                    int t = qbase + u*64 + wid*16 + 4*g + j;
                    AO[((size_t)(b*TT + t))*HIDDEN + h*HDIM + d] = f2b(accO[u][nt][j] * linv[j]);
                }
            }
        }
    }
}

extern "C" void kernel_launch(void* const* d_in, const int* in_sizes, int n_in,
                              void* d_out, int out_size, void* d_ws, size_t ws_size,
                              hipStream_t stream) {
    const float* x  = (const float*)d_in[0];
    const float* wq = (const float*)d_in[1];
    const float* bq = (const float*)d_in[2];
    const float* wk = (const float*)d_in[3];
    const float* bk = (const float*)d_in[4];
    const float* wv = (const float*)d_in[5];
    const float* bv = (const float*)d_in[6];
    const float* wo = (const float*)d_in[7];
    const float* bo = (const float*)d_in[8];

    char* ws = (char*)d_ws;
    const size_t szXb = (size_t)BT*HIDDEN*2;          // 18874368
    const size_t szW  = (size_t)HIDDEN*HIDDEN*2;      // 2654208
    const size_t szQp = (size_t)NB*HEADS*TT*DPAD*2;   // 25165824

    unsigned short* Xb  = (unsigned short*)(ws);
    unsigned short* WTq = (unsigned short*)(ws + szXb);
    unsigned short* WTk = (unsigned short*)(ws + szXb + szW);
    unsigned short* WTv = (unsigned short*)(ws + szXb + 2*szW);
    unsigned short* WTo = (unsigned short*)(ws + szXb + 3*szW);
    unsigned short* Qp  = (unsigned short*)(ws + szXb + 4*szW);
    unsigned short* Kp  = (unsigned short*)(ws + szXb + 4*szW + szQp);
    unsigned short* Vt  = (unsigned short*)(ws + szXb + 4*szW + 2*szQp);
    unsigned short* AO  = (unsigned short*)(ws + szXb + 4*szW + 3*szQp);

    hipMemsetAsync(Qp, 0, 3*szQp, stream);            // zero d-padding of Q, K, V (contiguous)

    k_convert_x<<<BT*HIDDEN/1024, 256, 0, stream>>>(x, Xb);
    k_wtrans<<<324, 256, 0, stream>>>(wq, WTq);
    k_wtrans<<<324, 256, 0, stream>>>(wk, WTk);
    k_wtrans<<<324, 256, 0, stream>>>(wv, WTv);
    k_wtrans<<<324, 256, 0, stream>>>(wo, WTo);

    const float qscale = (1.0f / sqrtf(72.0f)) * 1.44269504f;  // fold log2(e) for exp2 softmax
    k_gemm<0><<<576, 256, 0, stream>>>(Xb, WTq, bq, Qp, qscale);
    k_gemm<1><<<576, 256, 0, stream>>>(Xb, WTk, bk, Kp, 1.0f);
    k_gemm<2><<<576, 256, 0, stream>>>(Xb, WTv, bv, Vt, 1.0f);

    k_attn<<<NB*HEADS*(TT/128), 256, 0, stream>>>(Qp, Kp, Vt, AO);

    k_gemm<3><<<576, 256, 0, stream>>>(AO, WTo, bo, d_out, 1.0f);
}